// Round 10
// baseline (100.280 us; speedup 1.0000x reference)
//
#include <hip/hip_runtime.h>
#include <math.h>

typedef __bf16 bf16;
typedef __bf16 bf16x2 __attribute__((ext_vector_type(2)));
typedef __bf16 bf16x4 __attribute__((ext_vector_type(4)));
typedef __bf16 bf16x8 __attribute__((ext_vector_type(8)));
typedef float  f32x4  __attribute__((ext_vector_type(4)));

#define BZd 16
#define INd 512
#define Sd  512
#define Od  512
#define Ld  2048
#define CLd 128
#define NCd (Ld / CLd)   // 16 chunks of 128

__device__ __forceinline__ int keyf(int r) { return (r & 3) ^ ((r >> 2) & 3); }

// ---- prep_all: 0-255 conv B, 256-511 conv C, 512-767 conv D (+dfa), 768 A_diag
__global__ __launch_bounds__(256) void prep_all(const float* __restrict__ B,
                                                const float* __restrict__ C,
                                                const float* __restrict__ D,
                                                const float* __restrict__ Au,
                                                bf16* __restrict__ Bb, bf16* __restrict__ Cb,
                                                bf16* __restrict__ Db, float* __restrict__ A_diag,
                                                int* __restrict__ dfa) {
    __shared__ int sred[4];
    int bid = blockIdx.x;
    if (bid == 768) {
        #pragma unroll
        for (int r = 0; r < 2; ++r) {
            int ss = threadIdx.x + r * 256;
            float x = Au[ss];
            float sp = fmaxf(x, 0.0f) + log1pf(expf(-fabsf(x)));
            A_diag[ss] = -sp;
        }
        return;
    }
    int which = bid >> 8, lb = bid & 255;
    const float* src = which == 0 ? B : (which == 1 ? C : D);
    bf16* dst = which == 0 ? Bb : (which == 1 ? Cb : Db);
    int i = lb * 256 + threadIdx.x;
    f32x4 v = *(const f32x4*)&src[(size_t)i * 4];
    bf16x4 o = { (bf16)v[0], (bf16)v[1], (bf16)v[2], (bf16)v[3] };
    *(bf16x4*)&dst[(size_t)i * 4] = o;
    if (which == 2) {
        int nz = (v[0] != 0.f) | (v[1] != 0.f) | (v[2] != 0.f) | (v[3] != 0.f);
        unsigned long long bl = __ballot(nz);
        int wv = threadIdx.x >> 6;
        if ((threadIdx.x & 63) == 0) sred[wv] = (bl != 0ull);
        __syncthreads();
        if (threadIdx.x == 0) dfa[lb] = sred[0] | sred[1] | sred[2] | sred[3];
    }
}

// ---- gemm_bu 128x128: Bu tile + fused chunk-end scan ----
// M=l(2048) by 'by' (16), N=s(512) by 'bx' (4), K=i(512), 16 BK=32 units.
// 4 waves (2m x 2n), per-wave 64x64 (acc 64 regs) -> 2 blocks/CU co-resident.
// A staged from f32 u via reg-transpose into 2 LDS slots (XOR-swizzled ds_write);
// B via global_load_lds 2-ahead into 3 slots; 1 s_barrier/iter, vmcnt(2) steady gate.
__global__ __launch_bounds__(256, 2) void gemm_bu128(
    const float* __restrict__ Uf,
    const bf16* __restrict__ Bbf,
    const float* __restrict__ A_diag,
    float* __restrict__ ce,
    bf16* __restrict__ xs)
{
    constexpr int ASLOT = 128 * 32;   // 8 KiB
    constexpr int BSLOT = 128 * 32;   // 8 KiB
    __shared__ bf16 lds[2 * ASLOT + 3 * BSLOT];   // 40 KiB

    const int tid = threadIdx.x, lane = tid & 63, w = tid >> 6;

    int nwg = gridDim.x, bid = blockIdx.x;          // 1024 blocks, %8==0
    int cpx = nwg >> 3;
    int swz = (bid & 7) * cpx + (bid >> 3);
    int b  = swz >> 6;          // 4*16 = 64 blocks per batch
    int r0 = swz & 63;
    int by = r0 >> 2;           // 0..15  (l chunk)
    int bx = r0 & 3;            // 0..3   (s)

    const int wm = w >> 1, wn = w & 1;
    const int fr = lane & 15, g = lane >> 4;
    const int iq = tid & 7, lq = tid >> 3;          // lq 0..31

    const float* Ub = Uf + (size_t)b * INd * Ld;
    const bf16*  Bp = Bbf + (size_t)(bx * 128) * 512;

    f32x4 acc[4][4];
    #pragma unroll
    for (int i = 0; i < 4; ++i)
        #pragma unroll
        for (int j = 0; j < 4; ++j)
            acc[i][j] = (f32x4){0.f, 0.f, 0.f, 0.f};

    f32x4 areg[4];

    #define GLD16B(srcP, dstElem) __builtin_amdgcn_global_load_lds( \
        (const __attribute__((address_space(1))) void*)(srcP), \
        (__attribute__((address_space(3))) void*)&lds[dstElem], 16, 0, 0)

    auto issueA = [&](int U) {      // 4x f32x4 from u rows k, cols l (contig)
        #pragma unroll
        for (int d = 0; d < 4; ++d)
            areg[d] = *(const f32x4*)&Ub[(size_t)(U * 32 + iq * 4 + d) * Ld + by * 128 + lq * 4];
    };
    auto writeA = [&](int U) {      // transpose 4i x 4l micro-block, swizzled chunks
        bf16* As = &lds[(U & 1) * ASLOT];
        #pragma unroll
        for (int dl = 0; dl < 4; ++dl) {
            int r = lq * 4 + dl;    // 0..127
            bf16x4 wv = { (bf16)areg[0][dl], (bf16)areg[1][dl], (bf16)areg[2][dl], (bf16)areg[3][dl] };
            *(bf16x4*)&As[r * 32 + (((iq >> 1) ^ keyf(r)) * 8) + (iq & 1) * 4] = wv;
        }
    };
    auto gldB = [&](int U) {
        #pragma unroll
        for (int rb = 0; rb < 2; ++rb) {
            int row = rb * 64 + (tid >> 2);
            int cs = (tid & 3) ^ keyf(row);
            GLD16B(Bp + (size_t)row * 512 + U * 32 + cs * 8,
                   2 * ASLOT + (U % 3) * BSLOT + (rb * 64 + w * 16) * 32);
        }
    };

    // prologue: areg(0) + B(0) + B(1) in flight (order matters for vmcnt)
    issueA(0);
    __builtin_amdgcn_sched_barrier(0);
    gldB(0); gldB(1);
    __builtin_amdgcn_sched_barrier(0);

    for (int U = 0; U < 16; ++U) {
        if (U < 15) { asm volatile("s_waitcnt vmcnt(2)" ::: "memory"); }
        else        { asm volatile("s_waitcnt vmcnt(0)" ::: "memory"); }
        __builtin_amdgcn_sched_barrier(0);
        writeA(U);
        asm volatile("s_waitcnt lgkmcnt(0)" ::: "memory");
        __builtin_amdgcn_sched_barrier(0);
        __builtin_amdgcn_s_barrier();
        __builtin_amdgcn_sched_barrier(0);
        if (U + 1 < 16) {
            issueA(U + 1);
            __builtin_amdgcn_sched_barrier(0);
        }
        bf16x8 av[4], bv[4];
        {
            const bf16* As = &lds[(U & 1) * ASLOT];
            const bf16* Bs = &lds[2 * ASLOT + (U % 3) * BSLOT];
            #pragma unroll
            for (int i = 0; i < 4; ++i) {
                int R = wm * 64 + i * 16 + fr;
                av[i] = *(const bf16x8*)&As[R * 32 + (g ^ keyf(R)) * 8];
            }
            #pragma unroll
            for (int j = 0; j < 4; ++j) {
                int R = wn * 64 + j * 16 + fr;
                bv[j] = *(const bf16x8*)&Bs[R * 32 + (g ^ keyf(R)) * 8];
            }
        }
        if (U + 2 < 16) {
            gldB(U + 2);
            __builtin_amdgcn_sched_barrier(0);
        }
        __builtin_amdgcn_s_setprio(1);
        #pragma unroll
        for (int i = 0; i < 4; ++i)
            #pragma unroll
            for (int j = 0; j < 4; ++j)
                acc[i][j] = __builtin_amdgcn_mfma_f32_16x16x32_bf16(av[i], bv[j], acc[i][j], 0, 0, 0);
        __builtin_amdgcn_s_setprio(0);
    }

    int n0 = bx * 128 + wn * 64 + fr;     // s column
    int m0 = by * 128 + wm * 64 + g * 4;  // l row

    // ---- fused zero-init chunk-end scan over this block's 128 l-rows ----
    __syncthreads();                       // all LDS reads done; reuse as scratch
    float* scf = (float*)lds;              // [128] per-column 64-row partial (wm0)
    float Sv[4], a64j[4];
    #pragma unroll
    for (int j = 0; j < 4; ++j) {
        float a = A_diag[n0 + j * 16];
        float a2 = a * a, a4 = a2 * a2, a8 = a4 * a4, a16 = a8 * a8;
        float a32 = a16 * a16;
        a64j[j] = a32 * a32;
        float S = 0.f;
        #pragma unroll
        for (int i = 0; i < 4; ++i) {
            f32x4 v = acc[i][j];
            float e = fmaf(fmaf(fmaf(v[0], a, v[1]), a, v[2]), a, v[3]);
            float e0 = __shfl(e, fr), e1 = __shfl(e, fr + 16);
            float e2 = __shfl(e, fr + 32), e3 = __shfl(e, fr + 48);
            float E = fmaf(fmaf(fmaf(e0, a4, e1), a4, e2), a4, e3);
            S = fmaf(S, a16, E);
        }
        Sv[j] = S;
    }
    if (wm == 0 && g == 0) {
        #pragma unroll
        for (int j = 0; j < 4; ++j) scf[wn * 64 + j * 16 + fr] = Sv[j];
    }
    __syncthreads();
    if (wm == 1 && g == 0) {
        #pragma unroll
        for (int j = 0; j < 4; ++j) {
            float S0 = scf[wn * 64 + j * 16 + fr];
            ce[((size_t)b * NCd + by) * Sd + n0 + j * 16] = fmaf(S0, a64j[j], Sv[j]);
        }
    }

    // ---- store xs (bf16): C/D layout col=lane&15, row=(lane>>4)*4+reg ----
    bf16* out = xs + (size_t)b * Ld * Sd;
    #pragma unroll
    for (int i = 0; i < 4; ++i)
        #pragma unroll
        for (int j = 0; j < 4; ++j)
            #pragma unroll
            for (int q = 0; q < 4; ++q)
                out[(size_t)(m0 + i * 16 + q) * Sd + n0 + j * 16] = (bf16)acc[i][j][q];
    #undef GLD16B
}

// ---- gemm_y (unchanged from R9): 256x256, 8 waves, A/B via global_load_lds ----
template<int AREG, int SCAN>
__global__ __launch_bounds__(512, 2) void gemm8p(
    const bf16* __restrict__ Abf, size_t aBS,
    const float* __restrict__ Uf, size_t uBS,
    const bf16* __restrict__ Bbf, size_t bBS,
    const bf16* __restrict__ Dbf,
    const int* __restrict__ dfa,
    const float* __restrict__ A_diag, float* __restrict__ cePtr,
    void* __restrict__ OutV, size_t oBS, int ldOut,
    int NX, int NY)
{
    constexpr int RS   = 32;
    constexpr int ASZ  = 256 * RS;
    constexpr int SLOT = ASZ + 256 * 32;
    __shared__ bf16 lds[4 * SLOT];

    const int tid = threadIdx.x;
    const int lane = tid & 63, w = tid >> 6;

    int nwg = gridDim.x, bid = blockIdx.x;
    int cpx = nwg >> 3;
    int swz = (bid & 7) * cpx + (bid >> 3);
    int pb = NX * NY;
    int b  = swz / pb;
    int r0 = swz - b * pb;
    int by = r0 / NX;
    int bx = r0 - by * NX;

    const int wm = w >> 2, wn = w & 3;
    const int fr = lane & 15, g = lane >> 4;
    const int iq = tid & 7, lq = tid >> 3;

    const bf16*  Ab = Abf + (size_t)b * aBS + (size_t)(by * 256) * 512;
    const float* Ub = Uf ? (Uf + (size_t)b * uBS) : nullptr;
    const bf16*  Bp = Bbf + (size_t)b * bBS + (size_t)(bx * 256) * 512;

    int extra = 0;
    if (dfa) {
        int4 f = ((const int4*)dfa)[lane];
        extra = __any((f.x | f.y | f.z | f.w) != 0) ? 1 : 0;
    }

    f32x4 acc[8][4];
    #pragma unroll
    for (int i = 0; i < 8; ++i)
        #pragma unroll
        for (int j = 0; j < 4; ++j)
            acc[i][j] = (f32x4){0.f, 0.f, 0.f, 0.f};

    #define GLD16(srcP, dstElem) __builtin_amdgcn_global_load_lds( \
        (const __attribute__((address_space(1))) void*)(srcP), \
        (__attribute__((address_space(3))) void*)&lds[dstElem], 16, 0, 0)

    auto gldA = [&](int U) {
        #pragma unroll
        for (int rb = 0; rb < 2; ++rb) {
            int row = rb * 128 + (tid >> 2);
            int cs = (tid & 3) ^ keyf(row);
            GLD16(Ab + (size_t)row * 512 + U * 32 + cs * 8,
                  (U & 3) * SLOT + (rb * 128 + w * 16) * 32);
        }
    };
    auto gldB = [&](int U) {
        #pragma unroll
        for (int rb = 0; rb < 2; ++rb) {
            int row = rb * 128 + (tid >> 2);
            int cs = (tid & 3) ^ keyf(row);
            GLD16(Bp + (size_t)row * 512 + U * 32 + cs * 8,
                  (U & 3) * SLOT + ASZ + (rb * 128 + w * 16) * 32);
        }
    };
    auto readFrags = [&](int slot, bf16x8* avf, bf16x8* bvf) {
        const bf16* As = &lds[slot * SLOT];
        const bf16* Bs = &lds[slot * SLOT + ASZ];
        #pragma unroll
        for (int i = 0; i < 8; ++i) {
            int R = wm * 128 + i * 16 + fr;
            avf[i] = *(const bf16x8*)&As[R * RS + (g ^ keyf(R)) * 8];
        }
        #pragma unroll
        for (int j = 0; j < 4; ++j) {
            int R = wn * 64 + j * 16 + fr;
            bvf[j] = *(const bf16x8*)&Bs[R * 32 + (g ^ keyf(R)) * 8];
        }
    };

    gldA(0); gldB(0); gldA(1); gldB(1);

    for (int U = 0; U < 16; ++U) {
        if (U < 15) { asm volatile("s_waitcnt vmcnt(4)" ::: "memory"); }
        else        { asm volatile("s_waitcnt vmcnt(0)" ::: "memory"); }
        __builtin_amdgcn_sched_barrier(0);
        __builtin_amdgcn_s_barrier();
        __builtin_amdgcn_sched_barrier(0);
        bf16x8 av[8], bv[4];
        readFrags(U & 3, av, bv);
        if (U + 2 < 16) gldA(U + 2);
        if (U + 2 < 16) gldB(U + 2);
        __builtin_amdgcn_s_setprio(1);
        #pragma unroll
        for (int i = 0; i < 8; ++i)
            #pragma unroll
            for (int j = 0; j < 4; ++j)
                acc[i][j] = __builtin_amdgcn_mfma_f32_16x16x32_bf16(av[i], bv[j], acc[i][j], 0, 0, 0);
        __builtin_amdgcn_s_setprio(0);
    }

    // ---- cold pass (D != 0 only; correctness path) ----
    if (extra) {
        #pragma unroll 1
        for (int T = 0; T < 16; ++T) {
            int k0 = T * 32;
            __builtin_amdgcn_s_barrier();
            f32x4 r4[4];
            #pragma unroll
            for (int d = 0; d < 4; ++d)
                r4[d] = *(const f32x4*)&Ub[(size_t)(k0 + iq * 4 + d) * Ld + bx * 256 + lq * 4];
            #pragma unroll
            for (int rb = 0; rb < 2; ++rb) {
                int row = rb * 128 + (tid >> 2);
                int cs = (tid & 3) ^ keyf(row);
                GLD16(Dbf + (size_t)(by * 256 + row) * 512 + k0 + cs * 8,
                      (rb * 128 + w * 16) * 32);
            }
            asm volatile("s_waitcnt vmcnt(0)" ::: "memory");
            #pragma unroll
            for (int dl = 0; dl < 4; ++dl) {
                int r = lq * 4 + dl;
                bf16x4 wv = { (bf16)r4[0][dl], (bf16)r4[1][dl], (bf16)r4[2][dl], (bf16)r4[3][dl] };
                int e = ((iq >> 1) ^ keyf(r)) * 8 + (iq & 1) * 4;
                *(bf16x4*)&lds[ASZ + r * 32 + e] = wv;
            }
            asm volatile("s_waitcnt lgkmcnt(0)" ::: "memory");
            __builtin_amdgcn_s_barrier();
            bf16x8 av[8], bv[4];
            readFrags(0, av, bv);
            #pragma unroll
            for (int i = 0; i < 8; ++i)
                #pragma unroll
                for (int j = 0; j < 4; ++j)
                    acc[i][j] = __builtin_amdgcn_mfma_f32_16x16x32_bf16(av[i], bv[j], acc[i][j], 0, 0, 0);
        }
    }

    int n0 = bx * 256 + wn * 64 + fr;
    int m0 = by * 256 + wm * 128 + g * 4;
    float* out = (float*)OutV + (size_t)b * oBS;
    #pragma unroll
    for (int i = 0; i < 8; ++i)
        #pragma unroll
        for (int j = 0; j < 4; ++j)
            #pragma unroll
            for (int q = 0; q < 4; ++q)
                out[(size_t)(m0 + i * 16 + q) * ldOut + n0 + j * 16] = acc[i][j][q];
    #undef GLD16
}

// ---- scan pass: carry (redone per block from ce) + full in-place scan, bf16x2
__global__ __launch_bounds__(256) void pass_scan2(bf16* __restrict__ xbuf,
                                                  const float* __restrict__ A_diag,
                                                  const float* __restrict__ ce,
                                                  const float* __restrict__ h0) {
    int gI = blockIdx.x * 256 + threadIdx.x;
    int sp = gI & 255;
    int c = (gI >> 8) & (NCd - 1);
    int b = gI >> 12;
    int s = sp * 2;
    float a0 = A_diag[s], a1 = A_diag[s + 1];
    float acl0 = a0, acl1 = a1;
    #pragma unroll
    for (int i = 0; i < 7; ++i) { acl0 *= acl0; acl1 *= acl1; }   // a^128
    float x0 = h0[s], x1 = h0[s + 1];
    for (int cp = 0; cp < NCd; ++cp) {
        if (cp >= c) break;
        float2 e = *(const float2*)&ce[((size_t)b * NCd + cp) * Sd + s];
        x0 = fmaf(acl0, x0, e.x);
        x1 = fmaf(acl1, x1, e.y);
    }
    bf16* p = xbuf + ((size_t)b * Ld + (size_t)c * CLd) * Sd + s;
    #pragma unroll 4
    for (int j = 0; j < CLd; ++j) {
        bf16x2 v = *(const bf16x2*)&p[(size_t)j * Sd];
        x0 = fmaf(a0, x0, (float)v[0]);
        x1 = fmaf(a1, x1, (float)v[1]);
        bf16x2 o = { (bf16)x0, (bf16)x1 };
        *(bf16x2*)&p[(size_t)j * Sd] = o;
    }
}

extern "C" void kernel_launch(void* const* d_in, const int* in_sizes, int n_in,
                              void* d_out, int out_size, void* d_ws, size_t ws_size,
                              hipStream_t stream) {
    const float* u  = (const float*)d_in[0];
    const float* Au = (const float*)d_in[1];
    const float* Bm = (const float*)d_in[2];
    const float* Cm = (const float*)d_in[3];
    const float* Dm = (const float*)d_in[4];
    const float* h0 = (const float*)d_in[5];
    float* Y = (float*)d_out;

    char* ws = (char*)d_ws;
    bf16* xs = (bf16*)ws;                              // 32 MiB: Bu -> scanned xs (bf16)
    bf16* Bb = (bf16*)(ws + (32ull << 20));            // 512 KiB each
    bf16* Cb = Bb + 262144;
    bf16* Db = Cb + 262144;
    float* A_diag = (float*)(ws + (32ull << 20) + 3ull * 524288);   // 2 KiB
    float* ce     = A_diag + 512;                      // 16*16*512 f32 = 512 KiB
    int*   dfa    = (int*)(ce + (size_t)BZd * NCd * Sd);  // 256 ints, written every call

    prep_all<<<769, 256, 0, stream>>>(Bm, Cm, Dm, Au, Bb, Cb, Db, A_diag, dfa);

    // gemm_bu: 128x128 tiles, grid 4*16*16 = 1024 (2 blocks/CU), fused ce epilogue
    gemm_bu128<<<1024, 256, 0, stream>>>(u, Bb, A_diag, ce, xs);

    pass_scan2<<<(BZd * NCd * (Sd / 2)) / 256, 256, 0, stream>>>(xs, A_diag, ce, h0);

    // gemm_y: M=o(512) via by (NY=2), N=l(2048) via bx (NX=8); A=Cb, B=xs; cold D pass iff D!=0
    gemm8p<0, 0><<<(Ld / 256) * (Od / 256) * BZd, 512, 0, stream>>>(
        Cb, 0, u, (size_t)INd * Ld, xs, (size_t)Ld * Sd, Db,
        dfa, A_diag, nullptr,
        (void*)Y, (size_t)Od * Ld, Ld,
        Ld / 256, Od / 256);
}

// Round 11
// 94.854 us; speedup vs baseline: 1.0572x; 1.0572x over previous
//
#include <hip/hip_runtime.h>
#include <math.h>

typedef __bf16 bf16;
typedef __bf16 bf16x2 __attribute__((ext_vector_type(2)));
typedef __bf16 bf16x4 __attribute__((ext_vector_type(4)));
typedef __bf16 bf16x8 __attribute__((ext_vector_type(8)));
typedef float  f32x4  __attribute__((ext_vector_type(4)));

#define BZd 16
#define INd 512
#define Sd  512
#define Od  512
#define Ld  2048
#define CLd 128
#define NCd (Ld / CLd)   // 16 chunks of 128

__device__ __forceinline__ int keyf(int r) { return (r & 3) ^ ((r >> 2) & 3); }

// ---- prep_all: 0-255 conv B, 256-511 conv C, 512-767 conv D (+dfa), 768 A_diag
__global__ __launch_bounds__(256) void prep_all(const float* __restrict__ B,
                                                const float* __restrict__ C,
                                                const float* __restrict__ D,
                                                const float* __restrict__ Au,
                                                bf16* __restrict__ Bb, bf16* __restrict__ Cb,
                                                bf16* __restrict__ Db, float* __restrict__ A_diag,
                                                int* __restrict__ dfa) {
    __shared__ int sred[4];
    int bid = blockIdx.x;
    if (bid == 768) {
        #pragma unroll
        for (int r = 0; r < 2; ++r) {
            int ss = threadIdx.x + r * 256;
            float x = Au[ss];
            float sp = fmaxf(x, 0.0f) + log1pf(expf(-fabsf(x)));
            A_diag[ss] = -sp;
        }
        return;
    }
    int which = bid >> 8, lb = bid & 255;
    const float* src = which == 0 ? B : (which == 1 ? C : D);
    bf16* dst = which == 0 ? Bb : (which == 1 ? Cb : Db);
    int i = lb * 256 + threadIdx.x;
    f32x4 v = *(const f32x4*)&src[(size_t)i * 4];
    bf16x4 o = { (bf16)v[0], (bf16)v[1], (bf16)v[2], (bf16)v[3] };
    *(bf16x4*)&dst[(size_t)i * 4] = o;
    if (which == 2) {
        int nz = (v[0] != 0.f) | (v[1] != 0.f) | (v[2] != 0.f) | (v[3] != 0.f);
        unsigned long long bl = __ballot(nz);
        int wv = threadIdx.x >> 6;
        if ((threadIdx.x & 63) == 0) sred[wv] = (bl != 0ull);
        __syncthreads();
        if (threadIdx.x == 0) dfa[lb] = sred[0] | sred[1] | sred[2] | sred[3];
    }
}

// ---- gemm_bu 128x128, 2-DEEP areg prefetch ----
// M=l(2048) by 'by' (16), N=s(512) by 'bx' (4), K=i(512), 16 BK=32 units.
// 4 waves (2m x 2n), per-wave 64x64. A: f32 u -> regs (2 named buffers, issued
// 2 iters ahead) -> swizzled ds_write (2 slots). B: global_load_lds 2-ahead (4 slots).
// Steady vmcnt(6) = {A(U+1)x4, B(U+1)x2} stay in flight. Unroll x4 for static regs.
__global__ __launch_bounds__(256, 3) void gemm_bu128(
    const float* __restrict__ Uf,
    const bf16* __restrict__ Bbf,
    const float* __restrict__ A_diag,
    float* __restrict__ ce,
    bf16* __restrict__ xs)
{
    constexpr int ASLOT = 128 * 32;   // 8 KiB
    constexpr int BSLOT = 128 * 32;   // 8 KiB
    __shared__ bf16 lds[2 * ASLOT + 4 * BSLOT];   // 48 KiB

    const int tid = threadIdx.x, lane = tid & 63, w = tid >> 6;

    int nwg = gridDim.x, bid = blockIdx.x;          // 1024 blocks, %8==0
    int cpx = nwg >> 3;
    int swz = (bid & 7) * cpx + (bid >> 3);
    int b  = swz >> 6;
    int r0 = swz & 63;
    int by = r0 >> 2;           // 0..15  (l chunk)
    int bx = r0 & 3;            // 0..3   (s)

    const int wm = w >> 1, wn = w & 1;
    const int fr = lane & 15, g = lane >> 4;
    const int iq = tid & 7, lq = tid >> 3;          // lq 0..31

    const float* Ub = Uf + (size_t)b * INd * Ld;
    const bf16*  Bp = Bbf + (size_t)(bx * 128) * 512;

    f32x4 acc[4][4];
    #pragma unroll
    for (int i = 0; i < 4; ++i)
        #pragma unroll
        for (int j = 0; j < 4; ++j)
            acc[i][j] = (f32x4){0.f, 0.f, 0.f, 0.f};

    f32x4 pA[4], pB[4];   // two named areg buffers (even / odd U)

    #define GLD16B(srcP, dstElem) __builtin_amdgcn_global_load_lds( \
        (const __attribute__((address_space(1))) void*)(srcP), \
        (__attribute__((address_space(3))) void*)&lds[dstElem], 16, 0, 0)

    auto issueA = [&](int U, f32x4 (&dst)[4]) {
        #pragma unroll
        for (int d = 0; d < 4; ++d)
            dst[d] = *(const f32x4*)&Ub[(size_t)(U * 32 + iq * 4 + d) * Ld + by * 128 + lq * 4];
    };
    auto writeA = [&](int U, f32x4 (&src)[4]) {
        bf16* As = &lds[(U & 1) * ASLOT];
        #pragma unroll
        for (int dl = 0; dl < 4; ++dl) {
            int r = lq * 4 + dl;
            bf16x4 wv = { (bf16)src[0][dl], (bf16)src[1][dl], (bf16)src[2][dl], (bf16)src[3][dl] };
            *(bf16x4*)&As[r * 32 + (((iq >> 1) ^ keyf(r)) * 8) + (iq & 1) * 4] = wv;
        }
    };
    auto gldB = [&](int U) {
        #pragma unroll
        for (int rb = 0; rb < 2; ++rb) {
            int row = rb * 64 + (tid >> 2);
            int cs = (tid & 3) ^ keyf(row);
            GLD16B(Bp + (size_t)row * 512 + U * 32 + cs * 8,
                   2 * ASLOT + (U & 3) * BSLOT + (rb * 64 + w * 16) * 32);
        }
    };
    auto step = [&](int U, f32x4 (&cur)[4]) {
        if (U < 15) { asm volatile("s_waitcnt vmcnt(6)" ::: "memory"); }
        else        { asm volatile("s_waitcnt vmcnt(0)" ::: "memory"); }
        __builtin_amdgcn_sched_barrier(0);
        writeA(U, cur);
        asm volatile("s_waitcnt lgkmcnt(0)" ::: "memory");
        __builtin_amdgcn_sched_barrier(0);
        __builtin_amdgcn_s_barrier();
        __builtin_amdgcn_sched_barrier(0);
        if (U + 2 < 16) {
            issueA(U + 2, cur);          // refill the buffer just drained
            __builtin_amdgcn_sched_barrier(0);
        }
        bf16x8 av[4], bv[4];
        {
            const bf16* As = &lds[(U & 1) * ASLOT];
            const bf16* Bs = &lds[2 * ASLOT + (U & 3) * BSLOT];
            #pragma unroll
            for (int i = 0; i < 4; ++i) {
                int R = wm * 64 + i * 16 + fr;
                av[i] = *(const bf16x8*)&As[R * 32 + (g ^ keyf(R)) * 8];
            }
            #pragma unroll
            for (int j = 0; j < 4; ++j) {
                int R = wn * 64 + j * 16 + fr;
                bv[j] = *(const bf16x8*)&Bs[R * 32 + (g ^ keyf(R)) * 8];
            }
        }
        if (U + 2 < 16) {
            gldB(U + 2);
            __builtin_amdgcn_sched_barrier(0);
        }
        __builtin_amdgcn_s_setprio(1);
        #pragma unroll
        for (int i = 0; i < 4; ++i)
            #pragma unroll
            for (int j = 0; j < 4; ++j)
                acc[i][j] = __builtin_amdgcn_mfma_f32_16x16x32_bf16(av[i], bv[j], acc[i][j], 0, 0, 0);
        __builtin_amdgcn_s_setprio(0);
    };

    // prologue: A0 -> pA, B0, A1 -> pB, B1   (queue: [A0x4, B0x2, A1x4, B1x2])
    issueA(0, pA);
    __builtin_amdgcn_sched_barrier(0);
    gldB(0);
    __builtin_amdgcn_sched_barrier(0);
    issueA(1, pB);
    __builtin_amdgcn_sched_barrier(0);
    gldB(1);
    __builtin_amdgcn_sched_barrier(0);

    // 16 units, unrolled x4 so areg parity (U&1) and B slot (U&3) are static
    for (int t = 0; t < 4; ++t) {
        step(4 * t + 0, pA);
        step(4 * t + 1, pB);
        step(4 * t + 2, pA);
        step(4 * t + 3, pB);
    }

    int n0 = bx * 128 + wn * 64 + fr;     // s column
    int m0 = by * 128 + wm * 64 + g * 4;  // l row

    // ---- fused zero-init chunk-end scan over this block's 128 l-rows ----
    __syncthreads();
    float* scf = (float*)lds;
    float Sv[4], a64j[4];
    #pragma unroll
    for (int j = 0; j < 4; ++j) {
        float a = A_diag[n0 + j * 16];
        float a2 = a * a, a4 = a2 * a2, a8 = a4 * a4, a16 = a8 * a8;
        float a32 = a16 * a16;
        a64j[j] = a32 * a32;
        float S = 0.f;
        #pragma unroll
        for (int i = 0; i < 4; ++i) {
            f32x4 v = acc[i][j];
            float e = fmaf(fmaf(fmaf(v[0], a, v[1]), a, v[2]), a, v[3]);
            float e0 = __shfl(e, fr), e1 = __shfl(e, fr + 16);
            float e2 = __shfl(e, fr + 32), e3 = __shfl(e, fr + 48);
            float E = fmaf(fmaf(fmaf(e0, a4, e1), a4, e2), a4, e3);
            S = fmaf(S, a16, E);
        }
        Sv[j] = S;
    }
    if (wm == 0 && g == 0) {
        #pragma unroll
        for (int j = 0; j < 4; ++j) scf[wn * 64 + j * 16 + fr] = Sv[j];
    }
    __syncthreads();
    if (wm == 1 && g == 0) {
        #pragma unroll
        for (int j = 0; j < 4; ++j) {
            float S0 = scf[wn * 64 + j * 16 + fr];
            ce[((size_t)b * NCd + by) * Sd + n0 + j * 16] = fmaf(S0, a64j[j], Sv[j]);
        }
    }

    // ---- store xs (bf16): C/D layout col=lane&15, row=(lane>>4)*4+reg ----
    bf16* out = xs + (size_t)b * Ld * Sd;
    #pragma unroll
    for (int i = 0; i < 4; ++i)
        #pragma unroll
        for (int j = 0; j < 4; ++j)
            #pragma unroll
            for (int q = 0; q < 4; ++q)
                out[(size_t)(m0 + i * 16 + q) * Sd + n0 + j * 16] = (bf16)acc[i][j][q];
    #undef GLD16B
}

// ---- gemm_y: 256x256, 8 waves, A/B via global_load_lds (unchanged) ----
template<int AREG, int SCAN>
__global__ __launch_bounds__(512, 2) void gemm8p(
    const bf16* __restrict__ Abf, size_t aBS,
    const float* __restrict__ Uf, size_t uBS,
    const bf16* __restrict__ Bbf, size_t bBS,
    const bf16* __restrict__ Dbf,
    const int* __restrict__ dfa,
    const float* __restrict__ A_diag, float* __restrict__ cePtr,
    void* __restrict__ OutV, size_t oBS, int ldOut,
    int NX, int NY)
{
    constexpr int RS   = 32;
    constexpr int ASZ  = 256 * RS;
    constexpr int SLOT = ASZ + 256 * 32;
    __shared__ bf16 lds[4 * SLOT];

    const int tid = threadIdx.x;
    const int lane = tid & 63, w = tid >> 6;

    int nwg = gridDim.x, bid = blockIdx.x;
    int cpx = nwg >> 3;
    int swz = (bid & 7) * cpx + (bid >> 3);
    int pb = NX * NY;
    int b  = swz / pb;
    int r0 = swz - b * pb;
    int by = r0 / NX;
    int bx = r0 - by * NX;

    const int wm = w >> 2, wn = w & 3;
    const int fr = lane & 15, g = lane >> 4;
    const int iq = tid & 7, lq = tid >> 3;

    const bf16*  Ab = Abf + (size_t)b * aBS + (size_t)(by * 256) * 512;
    const float* Ub = Uf ? (Uf + (size_t)b * uBS) : nullptr;
    const bf16*  Bp = Bbf + (size_t)b * bBS + (size_t)(bx * 256) * 512;

    int extra = 0;
    if (dfa) {
        int4 f = ((const int4*)dfa)[lane];
        extra = __any((f.x | f.y | f.z | f.w) != 0) ? 1 : 0;
    }

    f32x4 acc[8][4];
    #pragma unroll
    for (int i = 0; i < 8; ++i)
        #pragma unroll
        for (int j = 0; j < 4; ++j)
            acc[i][j] = (f32x4){0.f, 0.f, 0.f, 0.f};

    #define GLD16(srcP, dstElem) __builtin_amdgcn_global_load_lds( \
        (const __attribute__((address_space(1))) void*)(srcP), \
        (__attribute__((address_space(3))) void*)&lds[dstElem], 16, 0, 0)

    auto gldA = [&](int U) {
        #pragma unroll
        for (int rb = 0; rb < 2; ++rb) {
            int row = rb * 128 + (tid >> 2);
            int cs = (tid & 3) ^ keyf(row);
            GLD16(Ab + (size_t)row * 512 + U * 32 + cs * 8,
                  (U & 3) * SLOT + (rb * 128 + w * 16) * 32);
        }
    };
    auto gldB = [&](int U) {
        #pragma unroll
        for (int rb = 0; rb < 2; ++rb) {
            int row = rb * 128 + (tid >> 2);
            int cs = (tid & 3) ^ keyf(row);
            GLD16(Bp + (size_t)row * 512 + U * 32 + cs * 8,
                  (U & 3) * SLOT + ASZ + (rb * 128 + w * 16) * 32);
        }
    };
    auto readFrags = [&](int slot, bf16x8* avf, bf16x8* bvf) {
        const bf16* As = &lds[slot * SLOT];
        const bf16* Bs = &lds[slot * SLOT + ASZ];
        #pragma unroll
        for (int i = 0; i < 8; ++i) {
            int R = wm * 128 + i * 16 + fr;
            avf[i] = *(const bf16x8*)&As[R * RS + (g ^ keyf(R)) * 8];
        }
        #pragma unroll
        for (int j = 0; j < 4; ++j) {
            int R = wn * 64 + j * 16 + fr;
            bvf[j] = *(const bf16x8*)&Bs[R * 32 + (g ^ keyf(R)) * 8];
        }
    };

    gldA(0); gldB(0); gldA(1); gldB(1);

    for (int U = 0; U < 16; ++U) {
        if (U < 15) { asm volatile("s_waitcnt vmcnt(4)" ::: "memory"); }
        else        { asm volatile("s_waitcnt vmcnt(0)" ::: "memory"); }
        __builtin_amdgcn_sched_barrier(0);
        __builtin_amdgcn_s_barrier();
        __builtin_amdgcn_sched_barrier(0);
        bf16x8 av[8], bv[4];
        readFrags(U & 3, av, bv);
        if (U + 2 < 16) gldA(U + 2);
        if (U + 2 < 16) gldB(U + 2);
        __builtin_amdgcn_s_setprio(1);
        #pragma unroll
        for (int i = 0; i < 8; ++i)
            #pragma unroll
            for (int j = 0; j < 4; ++j)
                acc[i][j] = __builtin_amdgcn_mfma_f32_16x16x32_bf16(av[i], bv[j], acc[i][j], 0, 0, 0);
        __builtin_amdgcn_s_setprio(0);
    }

    // ---- cold pass (D != 0 only; correctness path) ----
    if (extra) {
        #pragma unroll 1
        for (int T = 0; T < 16; ++T) {
            int k0 = T * 32;
            __builtin_amdgcn_s_barrier();
            f32x4 r4[4];
            #pragma unroll
            for (int d = 0; d < 4; ++d)
                r4[d] = *(const f32x4*)&Ub[(size_t)(k0 + iq * 4 + d) * Ld + bx * 256 + lq * 4];
            #pragma unroll
            for (int rb = 0; rb < 2; ++rb) {
                int row = rb * 128 + (tid >> 2);
                int cs = (tid & 3) ^ keyf(row);
                GLD16(Dbf + (size_t)(by * 256 + row) * 512 + k0 + cs * 8,
                      (rb * 128 + w * 16) * 32);
            }
            asm volatile("s_waitcnt vmcnt(0)" ::: "memory");
            #pragma unroll
            for (int dl = 0; dl < 4; ++dl) {
                int r = lq * 4 + dl;
                bf16x4 wv = { (bf16)r4[0][dl], (bf16)r4[1][dl], (bf16)r4[2][dl], (bf16)r4[3][dl] };
                int e = ((iq >> 1) ^ keyf(r)) * 8 + (iq & 1) * 4;
                *(bf16x4*)&lds[ASZ + r * 32 + e] = wv;
            }
            asm volatile("s_waitcnt lgkmcnt(0)" ::: "memory");
            __builtin_amdgcn_s_barrier();
            bf16x8 av[8], bv[4];
            readFrags(0, av, bv);
            #pragma unroll
            for (int i = 0; i < 8; ++i)
                #pragma unroll
                for (int j = 0; j < 4; ++j)
                    acc[i][j] = __builtin_amdgcn_mfma_f32_16x16x32_bf16(av[i], bv[j], acc[i][j], 0, 0, 0);
        }
    }

    int n0 = bx * 256 + wn * 64 + fr;
    int m0 = by * 256 + wm * 128 + g * 4;
    float* out = (float*)OutV + (size_t)b * oBS;
    #pragma unroll
    for (int i = 0; i < 8; ++i)
        #pragma unroll
        for (int j = 0; j < 4; ++j)
            #pragma unroll
            for (int q = 0; q < 4; ++q)
                out[(size_t)(m0 + i * 16 + q) * ldOut + n0 + j * 16] = acc[i][j][q];
    #undef GLD16
}

// ---- scan pass: carry (redone per block from ce) + full in-place scan, bf16x2
__global__ __launch_bounds__(256) void pass_scan2(bf16* __restrict__ xbuf,
                                                  const float* __restrict__ A_diag,
                                                  const float* __restrict__ ce,
                                                  const float* __restrict__ h0) {
    int gI = blockIdx.x * 256 + threadIdx.x;
    int sp = gI & 255;
    int c = (gI >> 8) & (NCd - 1);
    int b = gI >> 12;
    int s = sp * 2;
    float a0 = A_diag[s], a1 = A_diag[s + 1];
    float acl0 = a0, acl1 = a1;
    #pragma unroll
    for (int i = 0; i < 7; ++i) { acl0 *= acl0; acl1 *= acl1; }   // a^128
    float x0 = h0[s], x1 = h0[s + 1];
    for (int cp = 0; cp < NCd; ++cp) {
        if (cp >= c) break;
        float2 e = *(const float2*)&ce[((size_t)b * NCd + cp) * Sd + s];
        x0 = fmaf(acl0, x0, e.x);
        x1 = fmaf(acl1, x1, e.y);
    }
    bf16* p = xbuf + ((size_t)b * Ld + (size_t)c * CLd) * Sd + s;
    #pragma unroll 4
    for (int j = 0; j < CLd; ++j) {
        bf16x2 v = *(const bf16x2*)&p[(size_t)j * Sd];
        x0 = fmaf(a0, x0, (float)v[0]);
        x1 = fmaf(a1, x1, (float)v[1]);
        bf16x2 o = { (bf16)x0, (bf16)x1 };
        *(bf16x2*)&p[(size_t)j * Sd] = o;
    }
}

extern "C" void kernel_launch(void* const* d_in, const int* in_sizes, int n_in,
                              void* d_out, int out_size, void* d_ws, size_t ws_size,
                              hipStream_t stream) {
    const float* u  = (const float*)d_in[0];
    const float* Au = (const float*)d_in[1];
    const float* Bm = (const float*)d_in[2];
    const float* Cm = (const float*)d_in[3];
    const float* Dm = (const float*)d_in[4];
    const float* h0 = (const float*)d_in[5];
    float* Y = (float*)d_out;

    char* ws = (char*)d_ws;
    bf16* xs = (bf16*)ws;                              // 32 MiB: Bu -> scanned xs (bf16)
    bf16* Bb = (bf16*)(ws + (32ull << 20));            // 512 KiB each
    bf16* Cb = Bb + 262144;
    bf16* Db = Cb + 262144;
    float* A_diag = (float*)(ws + (32ull << 20) + 3ull * 524288);   // 2 KiB
    float* ce     = A_diag + 512;                      // 16*16*512 f32 = 512 KiB
    int*   dfa    = (int*)(ce + (size_t)BZd * NCd * Sd);  // 256 ints, written every call

    prep_all<<<769, 256, 0, stream>>>(Bm, Cm, Dm, Au, Bb, Cb, Db, A_diag, dfa);

    // gemm_bu: 128x128 tiles, 2-deep areg pipeline, fused ce epilogue
    gemm_bu128<<<1024, 256, 0, stream>>>(u, Bb, A_diag, ce, xs);

    pass_scan2<<<(BZd * NCd * (Sd / 2)) / 256, 256, 0, stream>>>(xs, A_diag, ce, h0);

    // gemm_y: M=o(512) via by (NY=2), N=l(2048) via bx (NX=8); A=Cb, B=xs; cold D pass iff D!=0
    gemm8p<0, 0><<<(Ld / 256) * (Od / 256) * BZd, 512, 0, stream>>>(
        Cb, 0, u, (size_t)INd * Ld, xs, (size_t)Ld * Sd, Db,
        dfa, A_diag, nullptr,
        (void*)Y, (size_t)Od * Ld, Ld,
        Ld / 256, Od / 256);
}

// Round 12
// 94.355 us; speedup vs baseline: 1.0628x; 1.0053x over previous
//
#include <hip/hip_runtime.h>
#include <math.h>

typedef __bf16 bf16;
typedef __bf16 bf16x2 __attribute__((ext_vector_type(2)));
typedef __bf16 bf16x4 __attribute__((ext_vector_type(4)));
typedef __bf16 bf16x8 __attribute__((ext_vector_type(8)));
typedef float  f32x4  __attribute__((ext_vector_type(4)));

#define BZd 16
#define INd 512
#define Sd  512
#define Od  512
#define Ld  2048
#define CLd 128
#define NCd (Ld / CLd)   // 16 chunks of 128

__device__ __forceinline__ int keyf(int r) { return (r & 3) ^ ((r >> 2) & 3); }

// ---- prep_all: 0-255 conv B, 256-511 conv C, 512-767 conv D (+dfa), 768 A_diag
__global__ __launch_bounds__(256) void prep_all(const float* __restrict__ B,
                                                const float* __restrict__ C,
                                                const float* __restrict__ D,
                                                const float* __restrict__ Au,
                                                bf16* __restrict__ Bb, bf16* __restrict__ Cb,
                                                bf16* __restrict__ Db, float* __restrict__ A_diag,
                                                int* __restrict__ dfa) {
    __shared__ int sred[4];
    int bid = blockIdx.x;
    if (bid == 768) {
        #pragma unroll
        for (int r = 0; r < 2; ++r) {
            int ss = threadIdx.x + r * 256;
            float x = Au[ss];
            float sp = fmaxf(x, 0.0f) + log1pf(expf(-fabsf(x)));
            A_diag[ss] = -sp;
        }
        return;
    }
    int which = bid >> 8, lb = bid & 255;
    const float* src = which == 0 ? B : (which == 1 ? C : D);
    bf16* dst = which == 0 ? Bb : (which == 1 ? Cb : Db);
    int i = lb * 256 + threadIdx.x;
    f32x4 v = *(const f32x4*)&src[(size_t)i * 4];
    bf16x4 o = { (bf16)v[0], (bf16)v[1], (bf16)v[2], (bf16)v[3] };
    *(bf16x4*)&dst[(size_t)i * 4] = o;
    if (which == 2) {
        int nz = (v[0] != 0.f) | (v[1] != 0.f) | (v[2] != 0.f) | (v[3] != 0.f);
        unsigned long long bl = __ballot(nz);
        int wv = threadIdx.x >> 6;
        if ((threadIdx.x & 63) == 0) sred[wv] = (bl != 0ull);
        __syncthreads();
        if (threadIdx.x == 0) dfa[lb] = sred[0] | sred[1] | sred[2] | sred[3];
    }
}

// ---- transpose+convert u: [b][i][l] f32 -> u_t[b][l][i] bf16 (proven ~13us) ----
__global__ __launch_bounds__(256) void transp_u(const float* __restrict__ u,
                                                bf16* __restrict__ ut) {
    __shared__ bf16 t[64][73];
    int b = blockIdx.z, i0 = blockIdx.y * 64, l0 = blockIdx.x * 64;
    int tid = threadIdx.x, tx = tid & 15, ty = tid >> 4;
    const float* ub = u + ((size_t)b * INd + i0) * Ld + l0;
    #pragma unroll
    for (int r = 0; r < 4; ++r) {
        int il = r * 16 + ty;
        float4 v = *(const float4*)&ub[(size_t)il * Ld + tx * 4];
        t[il][tx * 4 + 0] = (bf16)v.x;
        t[il][tx * 4 + 1] = (bf16)v.y;
        t[il][tx * 4 + 2] = (bf16)v.z;
        t[il][tx * 4 + 3] = (bf16)v.w;
    }
    __syncthreads();
    bf16* uo = ut + ((size_t)b * Ld + l0) * INd + i0;
    #pragma unroll
    for (int it = 0; it < 2; ++it) {
        int q = it * 256 + tid;
        int lr = q >> 3;
        int ic = (q & 7) * 8;
        bf16x8 o;
        #pragma unroll
        for (int e = 0; e < 8; ++e) o[e] = t[ic + e][lr];
        *(bf16x8*)&uo[(size_t)lr * INd + ic] = o;
    }
}

// ---- 256x256 MFMA GEMM, BK=32 units, global_load_lds 2-ahead, vmcnt(4) gate ----
// SCAN=1 (gemm_bu): out bf16 + fused chunk-end scan (each wave's 128 M-rows = 1 chunk).
// SCAN=0 (gemm_y):  out f32; cold D*u pass when dfa says D!=0.
template<int SCAN>
__global__ __launch_bounds__(512, 2) void gemm8p(
    const bf16* __restrict__ Abf, size_t aBS,
    const float* __restrict__ Uf, size_t uBS,
    const bf16* __restrict__ Bbf, size_t bBS,
    const bf16* __restrict__ Dbf,
    const int* __restrict__ dfa,
    const float* __restrict__ A_diag, float* __restrict__ cePtr,
    void* __restrict__ OutV, size_t oBS, int ldOut,
    int NX, int NY)
{
    constexpr int RS   = 32;
    constexpr int ASZ  = 256 * RS;
    constexpr int SLOT = ASZ + 256 * 32;
    __shared__ bf16 lds[4 * SLOT];

    const int tid = threadIdx.x;
    const int lane = tid & 63, w = tid >> 6;

    int nwg = gridDim.x, bid = blockIdx.x;
    int cpx = nwg >> 3;
    int swz = (bid & 7) * cpx + (bid >> 3);
    int pb = NX * NY;
    int b  = swz / pb;
    int r0 = swz - b * pb;
    int by = r0 / NX;
    int bx = r0 - by * NX;

    const int wm = w >> 2, wn = w & 3;
    const int fr = lane & 15, g = lane >> 4;
    const int iq = tid & 7, lq = tid >> 3;

    const bf16*  Ab = Abf + (size_t)b * aBS + (size_t)(by * 256) * 512;
    const float* Ub = Uf ? (Uf + (size_t)b * uBS) : nullptr;
    const bf16*  Bp = Bbf + (size_t)b * bBS + (size_t)(bx * 256) * 512;

    int extra = 0;
    if (!SCAN && dfa) {
        int4 f = ((const int4*)dfa)[lane];
        extra = __any((f.x | f.y | f.z | f.w) != 0) ? 1 : 0;
    }

    f32x4 acc[8][4];
    #pragma unroll
    for (int i = 0; i < 8; ++i)
        #pragma unroll
        for (int j = 0; j < 4; ++j)
            acc[i][j] = (f32x4){0.f, 0.f, 0.f, 0.f};

    #define GLD16(srcP, dstElem) __builtin_amdgcn_global_load_lds( \
        (const __attribute__((address_space(1))) void*)(srcP), \
        (__attribute__((address_space(3))) void*)&lds[dstElem], 16, 0, 0)

    auto gldA = [&](int U) {
        #pragma unroll
        for (int rb = 0; rb < 2; ++rb) {
            int row = rb * 128 + (tid >> 2);
            int cs = (tid & 3) ^ keyf(row);
            GLD16(Ab + (size_t)row * 512 + U * 32 + cs * 8,
                  (U & 3) * SLOT + (rb * 128 + w * 16) * 32);
        }
    };
    auto gldB = [&](int U) {
        #pragma unroll
        for (int rb = 0; rb < 2; ++rb) {
            int row = rb * 128 + (tid >> 2);
            int cs = (tid & 3) ^ keyf(row);
            GLD16(Bp + (size_t)row * 512 + U * 32 + cs * 8,
                  (U & 3) * SLOT + ASZ + (rb * 128 + w * 16) * 32);
        }
    };
    auto readFrags = [&](int slot, bf16x8* avf, bf16x8* bvf) {
        const bf16* As = &lds[slot * SLOT];
        const bf16* Bs = &lds[slot * SLOT + ASZ];
        #pragma unroll
        for (int i = 0; i < 8; ++i) {
            int R = wm * 128 + i * 16 + fr;
            avf[i] = *(const bf16x8*)&As[R * RS + (g ^ keyf(R)) * 8];
        }
        #pragma unroll
        for (int j = 0; j < 4; ++j) {
            int R = wn * 64 + j * 16 + fr;
            bvf[j] = *(const bf16x8*)&Bs[R * 32 + (g ^ keyf(R)) * 8];
        }
    };

    gldA(0); gldB(0); gldA(1); gldB(1);

    for (int U = 0; U < 16; ++U) {
        if (U < 15) { asm volatile("s_waitcnt vmcnt(4)" ::: "memory"); }
        else        { asm volatile("s_waitcnt vmcnt(0)" ::: "memory"); }
        __builtin_amdgcn_sched_barrier(0);
        __builtin_amdgcn_s_barrier();
        __builtin_amdgcn_sched_barrier(0);
        bf16x8 av[8], bv[4];
        readFrags(U & 3, av, bv);
        if (U + 2 < 16) gldA(U + 2);
        if (U + 2 < 16) gldB(U + 2);
        __builtin_amdgcn_s_setprio(1);
        #pragma unroll
        for (int i = 0; i < 8; ++i)
            #pragma unroll
            for (int j = 0; j < 4; ++j)
                acc[i][j] = __builtin_amdgcn_mfma_f32_16x16x32_bf16(av[i], bv[j], acc[i][j], 0, 0, 0);
        __builtin_amdgcn_s_setprio(0);
    }

    // ---- cold pass (gemm_y, D != 0 only; correctness path) ----
    if (!SCAN && extra) {
        #pragma unroll 1
        for (int T = 0; T < 16; ++T) {
            int k0 = T * 32;
            __builtin_amdgcn_s_barrier();
            f32x4 r4[4];
            #pragma unroll
            for (int d = 0; d < 4; ++d)
                r4[d] = *(const f32x4*)&Ub[(size_t)(k0 + iq * 4 + d) * Ld + bx * 256 + lq * 4];
            #pragma unroll
            for (int rb = 0; rb < 2; ++rb) {
                int row = rb * 128 + (tid >> 2);
                int cs = (tid & 3) ^ keyf(row);
                GLD16(Dbf + (size_t)(by * 256 + row) * 512 + k0 + cs * 8,
                      (rb * 128 + w * 16) * 32);
            }
            asm volatile("s_waitcnt vmcnt(0)" ::: "memory");
            #pragma unroll
            for (int dl = 0; dl < 4; ++dl) {
                int r = lq * 4 + dl;
                bf16x4 wv = { (bf16)r4[0][dl], (bf16)r4[1][dl], (bf16)r4[2][dl], (bf16)r4[3][dl] };
                int e = ((iq >> 1) ^ keyf(r)) * 8 + (iq & 1) * 4;
                *(bf16x4*)&lds[ASZ + r * 32 + e] = wv;
            }
            asm volatile("s_waitcnt lgkmcnt(0)" ::: "memory");
            __builtin_amdgcn_s_barrier();
            bf16x8 av[8], bv[4];
            readFrags(0, av, bv);
            #pragma unroll
            for (int i = 0; i < 8; ++i)
                #pragma unroll
                for (int j = 0; j < 4; ++j)
                    acc[i][j] = __builtin_amdgcn_mfma_f32_16x16x32_bf16(av[i], bv[j], acc[i][j], 0, 0, 0);
        }
    }

    int n0 = bx * 256 + wn * 64 + fr;
    int m0 = by * 256 + wm * 128 + g * 4;

    // ---- fused chunk-end scan (gemm_bu): wave rows wm*128..+128 == chunk by*2+wm ----
    if (SCAN) {
        #pragma unroll
        for (int j = 0; j < 4; ++j) {
            float a = A_diag[n0 + j * 16];
            float a2 = a * a, a4 = a2 * a2, a8 = a4 * a4, a16 = a8 * a8;
            float S = 0.f;
            #pragma unroll
            for (int i = 0; i < 8; ++i) {
                f32x4 v = acc[i][j];
                float e = fmaf(fmaf(fmaf(v[0], a, v[1]), a, v[2]), a, v[3]);
                float e0 = __shfl(e, fr), e1 = __shfl(e, fr + 16);
                float e2 = __shfl(e, fr + 32), e3 = __shfl(e, fr + 48);
                float E = fmaf(fmaf(fmaf(e0, a4, e1), a4, e2), a4, e3);
                S = fmaf(S, a16, E);
            }
            if (g == 0)
                cePtr[((size_t)b * NCd + (by * 2 + wm)) * Sd + n0 + j * 16] = S;
        }
    }

    // ---- store: C/D layout col=lane&15, row=(lane>>4)*4+reg ----
    if (SCAN) {
        bf16* out = (bf16*)OutV + (size_t)b * oBS;
        #pragma unroll
        for (int i = 0; i < 8; ++i)
            #pragma unroll
            for (int j = 0; j < 4; ++j)
                #pragma unroll
                for (int q = 0; q < 4; ++q)
                    out[(size_t)(m0 + i * 16 + q) * ldOut + n0 + j * 16] = (bf16)acc[i][j][q];
    } else {
        float* out = (float*)OutV + (size_t)b * oBS;
        #pragma unroll
        for (int i = 0; i < 8; ++i)
            #pragma unroll
            for (int j = 0; j < 4; ++j)
                #pragma unroll
                for (int q = 0; q < 4; ++q)
                    out[(size_t)(m0 + i * 16 + q) * ldOut + n0 + j * 16] = acc[i][j][q];
    }
    #undef GLD16
}

// ---- scan pass: carry (redone per block from ce) + full in-place scan, bf16x2
__global__ __launch_bounds__(256) void pass_scan2(bf16* __restrict__ xbuf,
                                                  const float* __restrict__ A_diag,
                                                  const float* __restrict__ ce,
                                                  const float* __restrict__ h0) {
    int gI = blockIdx.x * 256 + threadIdx.x;
    int sp = gI & 255;
    int c = (gI >> 8) & (NCd - 1);
    int b = gI >> 12;
    int s = sp * 2;
    float a0 = A_diag[s], a1 = A_diag[s + 1];
    float acl0 = a0, acl1 = a1;
    #pragma unroll
    for (int i = 0; i < 7; ++i) { acl0 *= acl0; acl1 *= acl1; }   // a^128
    float x0 = h0[s], x1 = h0[s + 1];
    for (int cp = 0; cp < NCd; ++cp) {
        if (cp >= c) break;
        float2 e = *(const float2*)&ce[((size_t)b * NCd + cp) * Sd + s];
        x0 = fmaf(acl0, x0, e.x);
        x1 = fmaf(acl1, x1, e.y);
    }
    bf16* p = xbuf + ((size_t)b * Ld + (size_t)c * CLd) * Sd + s;
    #pragma unroll 4
    for (int j = 0; j < CLd; ++j) {
        bf16x2 v = *(const bf16x2*)&p[(size_t)j * Sd];
        x0 = fmaf(a0, x0, (float)v[0]);
        x1 = fmaf(a1, x1, (float)v[1]);
        bf16x2 o = { (bf16)x0, (bf16)x1 };
        *(bf16x2*)&p[(size_t)j * Sd] = o;
    }
}

extern "C" void kernel_launch(void* const* d_in, const int* in_sizes, int n_in,
                              void* d_out, int out_size, void* d_ws, size_t ws_size,
                              hipStream_t stream) {
    const float* u  = (const float*)d_in[0];
    const float* Au = (const float*)d_in[1];
    const float* Bm = (const float*)d_in[2];
    const float* Cm = (const float*)d_in[3];
    const float* Dm = (const float*)d_in[4];
    const float* h0 = (const float*)d_in[5];
    float* Y = (float*)d_out;

    char* ws = (char*)d_ws;
    bf16* xs = (bf16*)ws;                              // 32 MiB: Bu -> scanned xs (bf16)
    bf16* ut = (bf16*)(ws + (32ull << 20));            // 32 MiB
    bf16* Bb = (bf16*)(ws + (64ull << 20));            // 512 KiB each
    bf16* Cb = Bb + 262144;
    bf16* Db = Cb + 262144;
    float* A_diag = (float*)(ws + (64ull << 20) + 3ull * 524288);   // 2 KiB
    float* ce     = A_diag + 512;                      // 16*16*512 f32 = 512 KiB
    int*   dfa    = (int*)(ce + (size_t)BZd * NCd * Sd);  // 256 ints, written every call

    prep_all<<<769, 256, 0, stream>>>(Bm, Cm, Dm, Au, Bb, Cb, Db, A_diag, dfa);
    transp_u<<<dim3(Ld / 64, INd / 64, BZd), 256, 0, stream>>>(u, ut);

    // gemm_bu: M=l(2048) via by (NY=8), N=s(512) via bx (NX=2); A=ut (batched), B=Bb (shared)
    gemm8p<1><<<(Sd / 256) * (Ld / 256) * BZd, 512, 0, stream>>>(
        ut, (size_t)Ld * INd, nullptr, 0, Bb, 0, nullptr,
        nullptr, A_diag, ce,
        (void*)xs, (size_t)Ld * Sd, Sd,
        Sd / 256, Ld / 256);

    pass_scan2<<<(BZd * NCd * (Sd / 2)) / 256, 256, 0, stream>>>(xs, A_diag, ce, h0);

    // gemm_y: M=o(512) via by (NY=2), N=l(2048) via bx (NX=8); A=Cb, B=xs; cold D pass iff D!=0
    gemm8p<0><<<(Ld / 256) * (Od / 256) * BZd, 512, 0, stream>>>(
        Cb, 0, u, (size_t)INd * Ld, xs, (size_t)Ld * Sd, Db,
        dfa, A_diag, nullptr,
        (void*)Y, (size_t)Od * Ld, Ld,
        Ld / 256, Od / 256);
}